// Round 6
// baseline (286.127 us; speedup 1.0000x reference)
//
#include <hip/hip_runtime.h>
#include <cstdint>
#include <cstddef>

// KAN layer: out[b,j] = sum_{i,k} basis_k(tanh x[b,i]) * C[j,i,k]
// basis is 2-sparse (adjacent lo, lo+1); basis[...,12] == 0 -> K=12 per i.
// Fast path: materialize dense f16 A[8192][12288] (201 MB in d_ws, coalesced via
// LDS repack) + f16 B[256][12288]; GEMM with BM=64, BN=256 (full N -> A read once),
// BK=32, 16x16x32 f16 MFMA, global_load_lds w=16, K-split 12, fp32 atomic epilogue.

typedef _Float16 half2_v __attribute__((ext_vector_type(2)));
typedef __fp16  fp16x2  __attribute__((ext_vector_type(2)));
typedef _Float16 f16x8 __attribute__((ext_vector_type(8)));
typedef float f32x4 __attribute__((ext_vector_type(4)));

__device__ __forceinline__ half2_v u32_as_h2(uint32_t u) {
  union { uint32_t u; half2_v h; } c; c.u = u; return c.h;
}
__device__ __forceinline__ uint32_t h2_as_u32(half2_v h) {
  union { uint32_t u; half2_v h; } c; c.h = h; return c.u;
}
__device__ __forceinline__ half2_v cvt_pk_h2(float a, float b) {
  union { fp16x2 f; half2_v h; } c;
  c.f = __builtin_amdgcn_cvt_pkrtz(a, b);
  return c.h;
}
__device__ __forceinline__ float dot2f(half2_v a, half2_v b, float c) {
#if __has_builtin(__builtin_amdgcn_fdot2)
  return __builtin_amdgcn_fdot2(a, b, c, false);
#else
  return c + (float)a[0] * (float)b[0] + (float)a[1] * (float)b[1];
#endif
}
__device__ __forceinline__ uint16_t f16_bits(float v) {
  union { _Float16 h; uint16_t u; } c; c.h = (_Float16)v; return c.u;
}

// ---- shared basis-weight computation ----
__device__ __forceinline__ void kan_weights(float xin, const float* __restrict__ knots,
                                            float& w0, float& w1, int& lo) {
  float xc = tanhf(xin);
  xc = fminf(fmaxf(xc, -1.0f), 1.0f);
  int m = (int)((xc + 1.0f) * 7.5f);   // interval index; basis continuity makes +-1 ULP safe
  m = min(max(m, 0), 14);
  const float k0 = knots[m], k1 = knots[m + 1];
  const float inv = 1.0f / (k1 - k0 + 1e-8f);
  const float up = (xc - k0) * inv;
  const float dn = (k1 - xc) * inv;
  // m==0: up on basis[0] | 1<=m<=11: dn on basis[m-1], up on basis[m]
  // m==12: dn on basis[11] | m>=13: zero
  w0 = (m == 0) ? up : ((m <= 12) ? dn : 0.0f);
  w1 = (m >= 1 && m <= 11) ? up : 0.0f;
  lo = min(max(m - 1, 0), 11);
}

// ================= fast path: dense f16 GEMM =================
#define GM 8192
#define GN 256
#define GK 12288           // 1024 i * 12 k
#define KSPL 12
#define KPER (GK / KSPL)   // 1024
#define BM 64

__global__ __launch_bounds__(256)
void kan_prep_A(const float* __restrict__ x, const float* __restrict__ knots,
                uint32_t* __restrict__ Aw) {
  __shared__ uint32_t Sh[256 * 6];   // 6 KB staging for coalesced uint4 stores
  const int t = threadIdx.x;
  const int tid = blockIdx.x * 256 + t;   // (b,i) flat
  float w0, w1; int lo;
  kan_weights(x[tid], knots, w0, w1, lo);
  const uint32_t h0 = f16_bits(w0), h1 = f16_bits(w1);
#pragma unroll
  for (int wq = 0; wq < 6; ++wq) {
    const int ka = 2 * wq, kb = 2 * wq + 1;
    const uint32_t lo16 = (ka == lo) ? h0 : ((ka == lo + 1) ? h1 : 0u);
    const uint32_t hi16 = (kb == lo) ? h0 : ((kb == lo + 1) ? h1 : 0u);
    Sh[t * 6 + wq] = lo16 | (hi16 << 16);
  }
  __syncthreads();
  const uint4* S4 = (const uint4*)Sh;                 // 384 uint4
  uint4* O4 = (uint4*)(Aw + (size_t)blockIdx.x * 1536);
  O4[t] = S4[t];
  if (t < 128) O4[256 + t] = S4[256 + t];
}

__global__ __launch_bounds__(256)
void kan_prep_B(const float* __restrict__ coef, uint32_t* __restrict__ Bw) {
  const int tid = blockIdx.x * 256 + threadIdx.x;   // 256*1024 (j,i)
  const float* cp = coef + (size_t)tid * 13;
  uint32_t wds[6];
#pragma unroll
  for (int wq = 0; wq < 6; ++wq)
    wds[wq] = h2_as_u32(cvt_pk_h2(cp[2 * wq], cp[2 * wq + 1]));
  uint32_t* p = Bw + (size_t)tid * 6;
  *(uint2*)(p + 0) = make_uint2(wds[0], wds[1]);
  *(uint2*)(p + 2) = make_uint2(wds[2], wds[3]);
  *(uint2*)(p + 4) = make_uint2(wds[4], wds[5]);
}

__device__ __forceinline__ void load_lds16(const void* g, void* l) {
  __builtin_amdgcn_global_load_lds((const __attribute__((address_space(1))) void*)g,
                                   (__attribute__((address_space(3))) void*)l, 16, 0, 0);
}

__global__ __launch_bounds__(256)
void kan_gemm(const _Float16* __restrict__ A, const _Float16* __restrict__ B,
              float* __restrict__ out) {
  // A: [8192][12288] f16 row-major. B: [256][12288] f16 (N x K).
  // Block: BM=64 rows x full N=256, K-slice KPER. 4 waves; each wave owns a
  // 64x64 n-slice; A fragments broadcast from LDS to all waves.
  __shared__ __align__(16) char smem[20480];   // A-tile 4 KB | B-tile 16 KB
  char* As = smem;
  char* Bs = smem + 4096;

  const int t    = threadIdx.x;    // 0..255
  const int lane = t & 63;
  const int wv   = t >> 6;         // 0..3 -> n-slice
  const int m0   = blockIdx.x * BM;
  const int kbeg = blockIdx.z * KPER;

  const int fr = lane & 15;        // fragment row/col
  const int fq = lane >> 4;        // quad

  f32x4 acc[4][4];
#pragma unroll
  for (int a = 0; a < 4; ++a)
#pragma unroll
    for (int b = 0; b < 4; ++b) acc[a][b] = (f32x4){0.f, 0.f, 0.f, 0.f};

  // staging: 16-B chunks; chunk -> row = chunk>>2, kc = chunk&3.
  const int row0 = t >> 2, kc0 = t & 3;

  for (int kt = 0; kt < KPER / 32; ++kt) {
    const int k0 = kbeg + kt * 32;
    const _Float16* Ab = A + (size_t)m0 * GK + k0 + kc0 * 8;
    const _Float16* Bb = B + (size_t)0 * GK + k0 + kc0 * 8;
    load_lds16(Ab + (size_t)row0 * GK, As + t * 16);                 // A: 256 chunks
#pragma unroll
    for (int s = 0; s < 4; ++s)                                      // B: 1024 chunks
      load_lds16(Bb + (size_t)(row0 + 64 * s) * GK, Bs + (t + 256 * s) * 16);
    __syncthreads();   // drains vmcnt (async LDS stores) before reads

    f16x8 af[4], bf[4];
#pragma unroll
    for (int mi = 0; mi < 4; ++mi)
      af[mi] = *(const f16x8*)(As + (mi * 16 + fr) * 64 + fq * 16);
#pragma unroll
    for (int ni = 0; ni < 4; ++ni)
      bf[ni] = *(const f16x8*)(Bs + (wv * 64 + ni * 16 + fr) * 64 + fq * 16);

#pragma unroll
    for (int mi = 0; mi < 4; ++mi)
#pragma unroll
      for (int ni = 0; ni < 4; ++ni)
        acc[mi][ni] = __builtin_amdgcn_mfma_f32_16x16x32_f16(af[mi], bf[ni], acc[mi][ni], 0, 0, 0);

    __syncthreads();   // compute done before next stage overwrites
  }

#pragma unroll
  for (int mi = 0; mi < 4; ++mi) {
    const int gr = m0 + mi * 16 + fq * 4;
#pragma unroll
    for (int ni = 0; ni < 4; ++ni) {
      const int gc = wv * 64 + ni * 16 + fr;
#pragma unroll
      for (int r = 0; r < 4; ++r)
        atomicAdd(&out[(size_t)(gr + r) * GN + gc], acc[mi][ni][r]);
    }
  }
}

// ================= fallback: round-4 dot2 path =================
#define TI 8
#define BT 256
#define JT 32
#define ISPL 2
#define IRANGE (1024 / ISPL)
#define CH_STRIDE (8192 * TI)

__global__ __launch_bounds__(256)
void kan_prep_dot2(const float* __restrict__ x, const float* __restrict__ knots,
                   uint32_t* __restrict__ W2, uint8_t* __restrict__ LO2) {
  const int tid = blockIdx.x * 256 + threadIdx.x;
  const int b = tid >> 10;
  const int i = tid & 1023;
  float w0, w1; int lo;
  kan_weights(x[(size_t)b * 1024 + i], knots, w0, w1, lo);
  const int idx = (i >> 3) * CH_STRIDE + b * TI + (i & 7);
  W2[idx] = h2_as_u32(cvt_pk_h2(w0, w1));
  LO2[idx] = (uint8_t)lo;
}

template <bool USE_PREP>
__global__ __launch_bounds__(256)
void kan_dot2(const float* __restrict__ x, const float* __restrict__ coef,
              const float* __restrict__ knots,
              const uint32_t* __restrict__ W2, const uint8_t* __restrict__ LO2,
              float* __restrict__ out) {
  __shared__ uint32_t Plds[TI * 12 * JT];
  const int t    = threadIdx.x;
  const int b    = blockIdx.x * BT + t;
  const int j0   = blockIdx.y * JT;
  const int cbeg = blockIdx.z * (IRANGE / TI);

  float acc[JT];
#pragma unroll
  for (int q = 0; q < JT; ++q) acc[q] = 0.0f;

  const int s_jj   = t & 31;
  const int s_iloc = t >> 5;

  for (int c = cbeg; c < cbeg + IRANGE / TI; ++c) {
    const int i0 = c * TI;
    __syncthreads();
    {
      const float* cp0 = coef + ((size_t)(j0 + s_jj) * 1024 + (i0 + s_iloc)) * 13;
      float cv[13];
#pragma unroll
      for (int s = 0; s < 13; ++s) cv[s] = cp0[s];
#pragma unroll
      for (int r = 0; r < 12; ++r) {
        half2_v h; h[0] = (_Float16)cv[r]; h[1] = (_Float16)cv[r + 1];
        const int slot = ((s_jj >> 2) + r) & 7;
        Plds[(s_iloc * 12 + r) * 32 + slot * 4 + (s_jj & 3)] = h2_as_u32(h);
      }
    }
    uint32_t wr[TI]; int lor[TI];
    if constexpr (USE_PREP) {
      const uint4* wp = (const uint4*)(W2 + (size_t)c * CH_STRIDE + b * TI);
      const uint4 wa = wp[0], wb = wp[1];
      wr[0] = wa.x; wr[1] = wa.y; wr[2] = wa.z; wr[3] = wa.w;
      wr[4] = wb.x; wr[5] = wb.y; wr[6] = wb.z; wr[7] = wb.w;
      const uint2 lb = *(const uint2*)(LO2 + (size_t)c * CH_STRIDE + b * TI);
#pragma unroll
      for (int q = 0; q < 4; ++q) { lor[q] = (lb.x >> (8 * q)) & 0xff; lor[4 + q] = (lb.y >> (8 * q)) & 0xff; }
    } else {
      const float* xrow = x + (size_t)b * 1024 + i0;
      const float4 xa = *(const float4*)(xrow);
      const float4 xb = *(const float4*)(xrow + 4);
      const float xv[TI] = {xa.x, xa.y, xa.z, xa.w, xb.x, xb.y, xb.z, xb.w};
#pragma unroll
      for (int q = 0; q < TI; ++q) {
        float w0, w1; int lo;
        kan_weights(xv[q], knots, w0, w1, lo);
        wr[q] = h2_as_u32(cvt_pk_h2(w0, w1));
        lor[q] = lo;
      }
    }
    __syncthreads();

    const uint4* P4 = (const uint4*)Plds;
#pragma unroll
    for (int ii = 0; ii < TI; ++ii) {
      const half2_v hw = u32_as_h2(wr[ii]);
      const int lo = lor[ii];
      const int base = (ii * 12 + lo) * 8;
#pragma unroll
      for (int g = 0; g < 8; ++g) {
        const uint4 v = P4[base + ((g + lo) & 7)];
        acc[4 * g + 0] = dot2f(hw, u32_as_h2(v.x), acc[4 * g + 0]);
        acc[4 * g + 1] = dot2f(hw, u32_as_h2(v.y), acc[4 * g + 1]);
        acc[4 * g + 2] = dot2f(hw, u32_as_h2(v.z), acc[4 * g + 2]);
        acc[4 * g + 3] = dot2f(hw, u32_as_h2(v.w), acc[4 * g + 3]);
      }
    }
  }

  float* orow = out + (size_t)b * 256 + j0;
#pragma unroll
  for (int q = 0; q < JT; ++q) atomicAdd(orow + q, acc[q]);
}

extern "C" void kernel_launch(void* const* d_in, const int* in_sizes, int n_in,
                              void* d_out, int out_size, void* d_ws, size_t ws_size,
                              hipStream_t stream) {
  const float* x     = (const float*)d_in[0];
  const float* coef  = (const float*)d_in[1];
  const float* knots = (const float*)d_in[2];
  float* out = (float*)d_out;

  (void)hipMemsetAsync(out, 0, (size_t)out_size * sizeof(float), stream);

  const size_t nA = (size_t)GM * GK;               // f16 elements
  const size_t nB = (size_t)GN * GK;
  const size_t needG = (nA + nB) * 2;              // ~208 MB
  const size_t nW = (size_t)8192 * 1024;
  const size_t needD = nW * 5;                     // 42 MB

  if (ws_size >= needG) {
    _Float16* Aw = (_Float16*)d_ws;
    _Float16* Bw = Aw + nA;
    kan_prep_A<<<(int)(nW / 256), 256, 0, stream>>>(x, knots, (uint32_t*)Aw);
    kan_prep_B<<<(int)(nB / 12 / 256), 256, 0, stream>>>(coef, (uint32_t*)Bw);
    dim3 grid(GM / BM, 1, KSPL);                   // (128, 1, 12) = 1536 blocks
    kan_gemm<<<grid, 256, 0, stream>>>(Aw, Bw, out);
  } else if (ws_size >= needD) {
    uint32_t* W2 = (uint32_t*)d_ws;
    uint8_t*  LO2 = (uint8_t*)(W2 + nW);
    dim3 grid(8192 / BT, 256 / JT, ISPL);
    kan_prep_dot2<<<(int)(nW / 256), 256, 0, stream>>>(x, knots, W2, LO2);
    kan_dot2<true><<<grid, BT, 0, stream>>>(x, coef, knots, W2, LO2, out);
  } else {
    dim3 grid(8192 / BT, 256 / JT, ISPL);
    kan_dot2<false><<<grid, BT, 0, stream>>>(x, coef, knots, nullptr, nullptr, out);
  }
}

// Round 7
// 245.976 us; speedup vs baseline: 1.1632x; 1.1632x over previous
//
#include <hip/hip_runtime.h>
#include <cstdint>
#include <cstddef>

// KAN layer: out[b,j] = sum_{i,k} basis_k(tanh x[b,i]) * C[j,i,k]
// basis is 2-sparse (adjacent slots lo, lo+1), so pad to 16 slots/i and build the
// MFMA A-fragment IN REGISTERS from an 8-B record (w0,w1 f16 + lo) -- no dense A
// materialization, no A HBM stream. B padded f16 [256][16384] (8.4 MB, L2-resident).
// GEMM: BM=128 x BN=256 full-N, BK=64 (4 i), 16x16x32 f16 MFMA, W+B staged via
// global_load_lds behind one barrier, K-split 8 with fp32 atomic epilogue.

typedef _Float16 half2_v __attribute__((ext_vector_type(2)));
typedef __fp16  fp16x2  __attribute__((ext_vector_type(2)));
typedef _Float16 f16x8 __attribute__((ext_vector_type(8)));
typedef float f32x4 __attribute__((ext_vector_type(4)));

__device__ __forceinline__ half2_v u32_as_h2(uint32_t u) {
  union { uint32_t u; half2_v h; } c; c.u = u; return c.h;
}
__device__ __forceinline__ uint32_t h2_as_u32(half2_v h) {
  union { uint32_t u; half2_v h; } c; c.h = h; return c.u;
}
__device__ __forceinline__ half2_v cvt_pk_h2(float a, float b) {
  union { fp16x2 f; half2_v h; } c;
  c.f = __builtin_amdgcn_cvt_pkrtz(a, b);
  return c.h;
}
__device__ __forceinline__ float dot2f(half2_v a, half2_v b, float c) {
#if __has_builtin(__builtin_amdgcn_fdot2)
  return __builtin_amdgcn_fdot2(a, b, c, false);
#else
  return c + (float)a[0] * (float)b[0] + (float)a[1] * (float)b[1];
#endif
}
__device__ __forceinline__ uint16_t f16_bits(float v) {
  union { _Float16 h; uint16_t u; } c; c.h = (_Float16)v; return c.u;
}

// ---- shared basis-weight computation ----
__device__ __forceinline__ void kan_weights(float xin, const float* __restrict__ knots,
                                            float& w0, float& w1, int& lo) {
  float xc = tanhf(xin);
  xc = fminf(fmaxf(xc, -1.0f), 1.0f);
  int m = (int)((xc + 1.0f) * 7.5f);   // interval index; basis continuity makes +-1 ULP safe
  m = min(max(m, 0), 14);
  const float k0 = knots[m], k1 = knots[m + 1];
  const float inv = 1.0f / (k1 - k0 + 1e-8f);
  const float up = (xc - k0) * inv;
  const float dn = (k1 - xc) * inv;
  // m==0: up on slot 0 | 1<=m<=11: dn on m-1, up on m | m==12: dn on 11 | m>=13: zero
  w0 = (m == 0) ? up : ((m <= 12) ? dn : 0.0f);
  w1 = (m >= 1 && m <= 11) ? up : 0.0f;
  lo = min(max(m - 1, 0), 11);
}

__device__ __forceinline__ void load_lds16(const void* g, void* l) {
  __builtin_amdgcn_global_load_lds((const __attribute__((address_space(1))) void*)g,
                                   (__attribute__((address_space(3))) void*)l, 16, 0, 0);
}

// ================= fast path =================
#define GMM 8192
#define GNN 256
#define KI  16                 // padded slots per i
#define GK2 (1024 * KI)        // 16384
#define KSPL2 8
#define IPER (1024 / KSPL2)    // 128 i per split
#define BM2 128

// prep_W: per (b,i) record = w0|w1 (u32 packed f16) | lo<<32, layout [i][b] via
// LDS transpose so both read and write are coalesced.
__global__ __launch_bounds__(256)
void kan_prep_W(const float* __restrict__ x, const float* __restrict__ knots,
                uint64_t* __restrict__ Wr) {
  __shared__ uint64_t T[64 * 65];   // [i_local][b_local], pad 65 to break banks
  const int t = threadIdx.x, lane = t & 63, ty = t >> 6;
  const int b0 = blockIdx.x * 64, i0 = blockIdx.y * 64;
#pragma unroll 4
  for (int r = 0; r < 16; ++r) {
    const int bl = ty * 16 + r;
    const float xv = x[(size_t)(b0 + bl) * 1024 + i0 + lane];
    float w0, w1; int lo;
    kan_weights(xv, knots, w0, w1, lo);
    const uint32_t wp = (uint32_t)f16_bits(w0) | ((uint32_t)f16_bits(w1) << 16);
    T[lane * 65 + bl] = (uint64_t)wp | ((uint64_t)(uint32_t)lo << 32);
  }
  __syncthreads();
#pragma unroll 4
  for (int r = 0; r < 16; ++r) {
    const int il = ty * 16 + r;
    Wr[(size_t)(i0 + il) * 8192 + b0 + lane] = T[il * 65 + lane];
  }
}

// prep_B2: f16 B2[j][i*16 + s], s=0..11 from coef, 12..15 zero (slot12 unused: A=0 there).
__global__ __launch_bounds__(256)
void kan_prep_B2(const float* __restrict__ coef, uint32_t* __restrict__ B2) {
  const int tid = blockIdx.x * 256 + threadIdx.x;   // flat (j,i), 262144
  const float* cp = coef + (size_t)tid * 13;
  uint32_t w[8];
#pragma unroll
  for (int q = 0; q < 6; ++q) w[q] = h2_as_u32(cvt_pk_h2(cp[2 * q], cp[2 * q + 1]));
  w[6] = 0u; w[7] = 0u;
  uint4* p = (uint4*)(B2 + (size_t)tid * 8);
  p[0] = make_uint4(w[0], w[1], w[2], w[3]);
  p[1] = make_uint4(w[4], w[5], w[6], w[7]);
}

__global__ __launch_bounds__(256, 2)
void kan_gemm2(const uint64_t* __restrict__ Wr, const _Float16* __restrict__ B2,
               float* __restrict__ out) {
  // Bs: [n=256][64 slots x 2B] = 32 KB. Ws: [i_loc=4][m=128] u64 = 4 KB.
  __shared__ __align__(16) char Bs[256 * 128];
  __shared__ __align__(16) uint64_t Ws[4 * 128];

  const int t    = threadIdx.x;
  const int lane = t & 63;
  const int wv   = t >> 6;
  const int mw   = wv & 1;          // m-half of block
  const int nw   = wv >> 1;         // n-half of block
  const int fr   = lane & 15;
  const int fq   = lane >> 4;
  const int m0   = blockIdx.x * BM2;
  const int i00  = blockIdx.z * IPER;
  const int fb   = (fq & 1) * 2;    // this lane's u64-word base within the 16-slot row

  f32x4 acc[4][8];
#pragma unroll
  for (int a = 0; a < 4; ++a)
#pragma unroll
    for (int b = 0; b < 8; ++b) acc[a][b] = (f32x4){0.f, 0.f, 0.f, 0.f};

  for (int it = 0; it < IPER / 4; ++it) {
    const int i0 = i00 + it * 4;
    __syncthreads();   // previous iter's LDS readers done

    // stage B tile: 256 rows x 64 slots = 2048 16-B chunks (8/thread)
    {
      const _Float16* Bb = B2 + (size_t)i0 * KI;
#pragma unroll
      for (int s = 0; s < 8; ++s) {
        const int q = s * 256 + t;
        const int n = q >> 3, c = q & 7;
        load_lds16(Bb + (size_t)n * GK2 + c * 8, Bs + q * 16);
      }
      // stage W slice: 4 i x 128 m records = 256 16-B chunks (1/thread)
      const int wi = t >> 6, wm = (t & 63) * 2;
      load_lds16(Wr + (size_t)(i0 + wi) * 8192 + m0 + wm, (char*)Ws + t * 16);
    }
    __syncthreads();   // drains vmcnt: B + W both land here

#pragma unroll
    for (int ks = 0; ks < 2; ++ks) {
      const int iloc = ks * 2 + (fq >> 1);
      // build A fragments in registers from (wp, lo)
      f16x8 af[4];
#pragma unroll
      for (int mi = 0; mi < 4; ++mi) {
        const uint64_t rec = Ws[iloc * 128 + mw * 64 + mi * 16 + fr];
        const uint32_t wp = (uint32_t)rec;
        const uint32_t lo = (uint32_t)(rec >> 32);
        const int s64 = (int)(lo & 3) * 16;
        const uint64_t lo64 = (uint64_t)wp << s64;
        const uint64_t hi64 = ((lo & 3) == 3) ? (uint64_t)(wp >> 16) : 0ull;
        const uint32_t q0 = lo >> 2;
        const uint64_t wA = ((uint32_t)fb == q0) ? lo64
                            : (((uint32_t)fb == q0 + 1) ? hi64 : 0ull);
        const uint64_t wB = ((uint32_t)(fb + 1) == q0) ? lo64
                            : (((uint32_t)fb == q0) ? hi64 : 0ull);
        union { uint64_t u[2]; f16x8 v; } cv;
        cv.u[0] = wA; cv.u[1] = wB;
        af[mi] = cv.v;
      }
#pragma unroll
      for (int ni = 0; ni < 8; ++ni) {
        const f16x8 bf = *(const f16x8*)(Bs + (nw * 128 + ni * 16 + fr) * 128 + ks * 64 + fq * 16);
#pragma unroll
        for (int mi = 0; mi < 4; ++mi)
          acc[mi][ni] = __builtin_amdgcn_mfma_f32_16x16x32_f16(af[mi], bf, acc[mi][ni], 0, 0, 0);
      }
    }
  }

#pragma unroll
  for (int mi = 0; mi < 4; ++mi) {
    const int gr = m0 + mw * 64 + mi * 16 + fq * 4;
#pragma unroll
    for (int ni = 0; ni < 8; ++ni) {
      const int gc = nw * 128 + ni * 16 + fr;
#pragma unroll
      for (int r = 0; r < 4; ++r)
        atomicAdd(&out[(size_t)(gr + r) * GNN + gc], acc[mi][ni][r]);
    }
  }
}

// ================= fallback: round-4 dot2 path (proven) =================
#define TI 8
#define BT 256
#define JT 32
#define ISPL 2
#define IRANGE (1024 / ISPL)
#define CH_STRIDE (8192 * TI)

__global__ __launch_bounds__(256)
void kan_prep_dot2(const float* __restrict__ x, const float* __restrict__ knots,
                   uint32_t* __restrict__ W2, uint8_t* __restrict__ LO2) {
  const int tid = blockIdx.x * 256 + threadIdx.x;
  const int b = tid >> 10;
  const int i = tid & 1023;
  float w0, w1; int lo;
  kan_weights(x[(size_t)b * 1024 + i], knots, w0, w1, lo);
  const int idx = (i >> 3) * CH_STRIDE + b * TI + (i & 7);
  W2[idx] = h2_as_u32(cvt_pk_h2(w0, w1));
  LO2[idx] = (uint8_t)lo;
}

template <bool USE_PREP>
__global__ __launch_bounds__(256)
void kan_dot2(const float* __restrict__ x, const float* __restrict__ coef,
              const float* __restrict__ knots,
              const uint32_t* __restrict__ W2, const uint8_t* __restrict__ LO2,
              float* __restrict__ out) {
  __shared__ uint32_t Plds[TI * 12 * JT];
  const int t    = threadIdx.x;
  const int b    = blockIdx.x * BT + t;
  const int j0   = blockIdx.y * JT;
  const int cbeg = blockIdx.z * (IRANGE / TI);

  float acc[JT];
#pragma unroll
  for (int q = 0; q < JT; ++q) acc[q] = 0.0f;

  const int s_jj   = t & 31;
  const int s_iloc = t >> 5;

  for (int c = cbeg; c < cbeg + IRANGE / TI; ++c) {
    const int i0 = c * TI;
    __syncthreads();
    {
      const float* cp0 = coef + ((size_t)(j0 + s_jj) * 1024 + (i0 + s_iloc)) * 13;
      float cv[13];
#pragma unroll
      for (int s = 0; s < 13; ++s) cv[s] = cp0[s];
#pragma unroll
      for (int r = 0; r < 12; ++r) {
        half2_v h; h[0] = (_Float16)cv[r]; h[1] = (_Float16)cv[r + 1];
        const int slot = ((s_jj >> 2) + r) & 7;
        Plds[(s_iloc * 12 + r) * 32 + slot * 4 + (s_jj & 3)] = h2_as_u32(h);
      }
    }
    uint32_t wr[TI]; int lor[TI];
    if constexpr (USE_PREP) {
      const uint4* wp = (const uint4*)(W2 + (size_t)c * CH_STRIDE + b * TI);
      const uint4 wa = wp[0], wb = wp[1];
      wr[0] = wa.x; wr[1] = wa.y; wr[2] = wa.z; wr[3] = wa.w;
      wr[4] = wb.x; wr[5] = wb.y; wr[6] = wb.z; wr[7] = wb.w;
      const uint2 lb = *(const uint2*)(LO2 + (size_t)c * CH_STRIDE + b * TI);
#pragma unroll
      for (int q = 0; q < 4; ++q) { lor[q] = (lb.x >> (8 * q)) & 0xff; lor[4 + q] = (lb.y >> (8 * q)) & 0xff; }
    } else {
      const float* xrow = x + (size_t)b * 1024 + i0;
      const float4 xa = *(const float4*)(xrow);
      const float4 xb = *(const float4*)(xrow + 4);
      const float xv[TI] = {xa.x, xa.y, xa.z, xa.w, xb.x, xb.y, xb.z, xb.w};
#pragma unroll
      for (int q = 0; q < TI; ++q) {
        float w0, w1; int lo;
        kan_weights(xv[q], knots, w0, w1, lo);
        wr[q] = h2_as_u32(cvt_pk_h2(w0, w1));
        lor[q] = lo;
      }
    }
    __syncthreads();

    const uint4* P4 = (const uint4*)Plds;
#pragma unroll
    for (int ii = 0; ii < TI; ++ii) {
      const half2_v hw = u32_as_h2(wr[ii]);
      const int lo = lor[ii];
      const int base = (ii * 12 + lo) * 8;
#pragma unroll
      for (int g = 0; g < 8; ++g) {
        const uint4 v = P4[base + ((g + lo) & 7)];
        acc[4 * g + 0] = dot2f(hw, u32_as_h2(v.x), acc[4 * g + 0]);
        acc[4 * g + 1] = dot2f(hw, u32_as_h2(v.y), acc[4 * g + 1]);
        acc[4 * g + 2] = dot2f(hw, u32_as_h2(v.z), acc[4 * g + 2]);
        acc[4 * g + 3] = dot2f(hw, u32_as_h2(v.w), acc[4 * g + 3]);
      }
    }
  }

  float* orow = out + (size_t)b * 256 + j0;
#pragma unroll
  for (int q = 0; q < JT; ++q) atomicAdd(orow + q, acc[q]);
}

extern "C" void kernel_launch(void* const* d_in, const int* in_sizes, int n_in,
                              void* d_out, int out_size, void* d_ws, size_t ws_size,
                              hipStream_t stream) {
  const float* x     = (const float*)d_in[0];
  const float* coef  = (const float*)d_in[1];
  const float* knots = (const float*)d_in[2];
  float* out = (float*)d_out;

  (void)hipMemsetAsync(out, 0, (size_t)out_size * sizeof(float), stream);

  const size_t nWr = (size_t)GMM * 1024;                 // u64 records
  const size_t nB2 = (size_t)GNN * GK2;                  // f16
  const size_t needG = nWr * 8 + nB2 * 2;                // ~75.5 MB
  const size_t nW = (size_t)8192 * 1024;
  const size_t needD = nW * 5;                           // 42 MB

  if (ws_size >= needG) {
    uint64_t* Wr = (uint64_t*)d_ws;
    _Float16* B2 = (_Float16*)(Wr + nWr);
    kan_prep_W<<<dim3(8192 / 64, 1024 / 64), 256, 0, stream>>>(x, knots, Wr);
    kan_prep_B2<<<(int)((size_t)GNN * 1024 / 256), 256, 0, stream>>>(coef, (uint32_t*)B2);
    dim3 grid(GMM / BM2, 1, KSPL2);                      // (64, 1, 8) = 512 blocks
    kan_gemm2<<<grid, 256, 0, stream>>>(Wr, B2, out);
  } else if (ws_size >= needD) {
    uint32_t* W2 = (uint32_t*)d_ws;
    uint8_t*  LO2 = (uint8_t*)(W2 + nW);
    dim3 grid(8192 / BT, 256 / JT, ISPL);
    kan_prep_dot2<<<(int)(nW / 256), 256, 0, stream>>>(x, knots, W2, LO2);
    kan_dot2<true><<<grid, BT, 0, stream>>>(x, coef, knots, W2, LO2, out);
  } else {
    dim3 grid(8192 / BT, 256 / JT, ISPL);
    kan_dot2<false><<<grid, BT, 0, stream>>>(x, coef, knots, nullptr, nullptr, out);
  }
}

// Round 8
// 242.628 us; speedup vs baseline: 1.1793x; 1.0138x over previous
//
#include <hip/hip_runtime.h>
#include <cstdint>
#include <cstddef>

// KAN layer: out[b,j] = sum_{i,k} basis_k(tanh x[b,i]) * C[j,i,k]
// basis is 2-sparse (adjacent slots lo, lo+1); pad to 16 slots/i and build the
// MFMA A-fragment IN REGISTERS from an 8-B record (w0,w1 f16 + lo).
// R8: BM=128 x BN=128 (acc 64 AGPR -> 3 waves/SIMD), grid (64,2,8)=1024 blocks,
// XOR-swizzled Bs (swizzle applied on the GLOBAL side since global_load_lds is
// uniform-base + lane*16), 16x16x32 f16 MFMA, fp32 atomic epilogue.

typedef _Float16 half2_v __attribute__((ext_vector_type(2)));
typedef __fp16  fp16x2  __attribute__((ext_vector_type(2)));
typedef _Float16 f16x8 __attribute__((ext_vector_type(8)));
typedef float f32x4 __attribute__((ext_vector_type(4)));

__device__ __forceinline__ half2_v u32_as_h2(uint32_t u) {
  union { uint32_t u; half2_v h; } c; c.u = u; return c.h;
}
__device__ __forceinline__ uint32_t h2_as_u32(half2_v h) {
  union { uint32_t u; half2_v h; } c; c.h = h; return c.u;
}
__device__ __forceinline__ half2_v cvt_pk_h2(float a, float b) {
  union { fp16x2 f; half2_v h; } c;
  c.f = __builtin_amdgcn_cvt_pkrtz(a, b);
  return c.h;
}
__device__ __forceinline__ float dot2f(half2_v a, half2_v b, float c) {
#if __has_builtin(__builtin_amdgcn_fdot2)
  return __builtin_amdgcn_fdot2(a, b, c, false);
#else
  return c + (float)a[0] * (float)b[0] + (float)a[1] * (float)b[1];
#endif
}
__device__ __forceinline__ uint16_t f16_bits(float v) {
  union { _Float16 h; uint16_t u; } c; c.h = (_Float16)v; return c.u;
}

// ---- shared basis-weight computation ----
__device__ __forceinline__ void kan_weights(float xin, const float* __restrict__ knots,
                                            float& w0, float& w1, int& lo) {
  float xc = tanhf(xin);
  xc = fminf(fmaxf(xc, -1.0f), 1.0f);
  int m = (int)((xc + 1.0f) * 7.5f);   // interval index; basis continuity makes +-1 ULP safe
  m = min(max(m, 0), 14);
  const float k0 = knots[m], k1 = knots[m + 1];
  const float inv = 1.0f / (k1 - k0 + 1e-8f);
  const float up = (xc - k0) * inv;
  const float dn = (k1 - xc) * inv;
  // m==0: up on slot 0 | 1<=m<=11: dn on m-1, up on m | m==12: dn on 11 | m>=13: zero
  w0 = (m == 0) ? up : ((m <= 12) ? dn : 0.0f);
  w1 = (m >= 1 && m <= 11) ? up : 0.0f;
  lo = min(max(m - 1, 0), 11);
}

__device__ __forceinline__ void load_lds16(const void* g, void* l) {
  __builtin_amdgcn_global_load_lds((const __attribute__((address_space(1))) void*)g,
                                   (__attribute__((address_space(3))) void*)l, 16, 0, 0);
}

// ================= fast path =================
#define GMM 8192
#define GNN 256
#define KI  16                 // padded slots per i
#define GK2 (1024 * KI)        // 16384
#define KSPL2 8
#define IPER (1024 / KSPL2)    // 128 i per split
#define BM2 128
#define BN2 128

// prep_W: per (b,i) record = w0|w1 (u32 packed f16) | lo<<32, layout [i][b] via
// LDS transpose so both read and write are coalesced.
__global__ __launch_bounds__(256)
void kan_prep_W(const float* __restrict__ x, const float* __restrict__ knots,
                uint64_t* __restrict__ Wr) {
  __shared__ uint64_t T[64 * 65];   // [i_local][b_local], pad 65 to break banks
  const int t = threadIdx.x, lane = t & 63, ty = t >> 6;
  const int b0 = blockIdx.x * 64, i0 = blockIdx.y * 64;
#pragma unroll 4
  for (int r = 0; r < 16; ++r) {
    const int bl = ty * 16 + r;
    const float xv = x[(size_t)(b0 + bl) * 1024 + i0 + lane];
    float w0, w1; int lo;
    kan_weights(xv, knots, w0, w1, lo);
    const uint32_t wp = (uint32_t)f16_bits(w0) | ((uint32_t)f16_bits(w1) << 16);
    T[lane * 65 + bl] = (uint64_t)wp | ((uint64_t)(uint32_t)lo << 32);
  }
  __syncthreads();
#pragma unroll 4
  for (int r = 0; r < 16; ++r) {
    const int il = ty * 16 + r;
    Wr[(size_t)(i0 + il) * 8192 + b0 + lane] = T[il * 65 + lane];
  }
}

// prep_B2: f16 B2[j][i*16 + s], s=0..11 from coef, 12..15 zero (slot12 unused: A=0 there).
__global__ __launch_bounds__(256)
void kan_prep_B2(const float* __restrict__ coef, uint32_t* __restrict__ B2) {
  const int tid = blockIdx.x * 256 + threadIdx.x;   // flat (j,i), 262144
  const float* cp = coef + (size_t)tid * 13;
  uint32_t w[8];
#pragma unroll
  for (int q = 0; q < 6; ++q) w[q] = h2_as_u32(cvt_pk_h2(cp[2 * q], cp[2 * q + 1]));
  w[6] = 0u; w[7] = 0u;
  uint4* p = (uint4*)(B2 + (size_t)tid * 8);
  p[0] = make_uint4(w[0], w[1], w[2], w[3]);
  p[1] = make_uint4(w[4], w[5], w[6], w[7]);
}

__global__ __launch_bounds__(256)
void kan_gemm2(const uint64_t* __restrict__ Wr, const _Float16* __restrict__ B2,
               float* __restrict__ out) {
  // Bs: [n=128][8 chunks x 16B] XOR-swizzled = 16 KB. Ws: [i_loc=4][m=128] u64 = 4 KB.
  __shared__ __align__(16) char Bs[BN2 * 128];
  __shared__ __align__(16) uint64_t Ws[4 * 128];

  const int t    = threadIdx.x;
  const int lane = t & 63;
  const int wv   = t >> 6;
  const int mw   = wv & 1;          // m-half of block (64)
  const int nw   = wv >> 1;         // n-half of block (64)
  const int fr   = lane & 15;
  const int fq   = lane >> 4;
  const int m0   = blockIdx.x * BM2;
  const int n0   = blockIdx.y * BN2;
  const int i00  = blockIdx.z * IPER;
  const int fb   = (fq & 1) * 2;    // this lane's u64-word base within the 16-slot row

  f32x4 acc[4][4];
#pragma unroll
  for (int a = 0; a < 4; ++a)
#pragma unroll
    for (int b = 0; b < 4; ++b) acc[a][b] = (f32x4){0.f, 0.f, 0.f, 0.f};

  for (int it = 0; it < IPER / 4; ++it) {
    const int i0 = i00 + it * 4;
    __syncthreads();   // previous iter's LDS readers done

    // stage B tile: 128 rows x 64 slots = 1024 16-B chunks (4/thread).
    // LDS slot q holds global chunk (n = q>>3, c = (q&7) ^ (n&7)) -- XOR swizzle
    // applied on the global side (global_load_lds LDS addr is uniform base + lane*16).
    {
      const _Float16* Bb = B2 + (size_t)i0 * KI;
#pragma unroll
      for (int s = 0; s < 4; ++s) {
        const int q = s * 256 + t;
        const int n = q >> 3, c = (q & 7) ^ (n & 7);
        load_lds16(Bb + (size_t)(n0 + n) * GK2 + c * 8, Bs + q * 16);
      }
      // stage W slice: 4 i x 128 m records = 256 16-B chunks (1/thread)
      const int wi = t >> 6, wm = (t & 63) * 2;
      load_lds16(Wr + (size_t)(i0 + wi) * 8192 + m0 + wm, (char*)Ws + t * 16);
    }
    __syncthreads();   // drains vmcnt: B + W both land here

#pragma unroll
    for (int ks = 0; ks < 2; ++ks) {
      const int iloc = ks * 2 + (fq >> 1);
      // build A fragments in registers from (wp, lo)
      f16x8 af[4];
#pragma unroll
      for (int mi = 0; mi < 4; ++mi) {
        const uint64_t rec = Ws[iloc * 128 + mw * 64 + mi * 16 + fr];
        const uint32_t wp = (uint32_t)rec;
        const uint32_t lo = (uint32_t)(rec >> 32);
        const int s64 = (int)(lo & 3) * 16;
        const uint64_t lo64 = (uint64_t)wp << s64;
        const uint64_t hi64 = ((lo & 3) == 3) ? (uint64_t)(wp >> 16) : 0ull;
        const uint32_t q0 = lo >> 2;
        const uint64_t wA = ((uint32_t)fb == q0) ? lo64
                            : (((uint32_t)fb == q0 + 1) ? hi64 : 0ull);
        const uint64_t wB = ((uint32_t)(fb + 1) == q0) ? lo64
                            : (((uint32_t)fb == q0) ? hi64 : 0ull);
        union { uint64_t u[2]; f16x8 v; } cv;
        cv.u[0] = wA; cv.u[1] = wB;
        af[mi] = cv.v;
      }
#pragma unroll
      for (int ni = 0; ni < 4; ++ni) {
        const int row = nw * 64 + ni * 16 + fr;
        const int col = ks * 4 + fq;
        const f16x8 bf = *(const f16x8*)(Bs + (row * 8 + (col ^ (row & 7))) * 16);
#pragma unroll
        for (int mi = 0; mi < 4; ++mi)
          acc[mi][ni] = __builtin_amdgcn_mfma_f32_16x16x32_f16(af[mi], bf, acc[mi][ni], 0, 0, 0);
      }
    }
  }

#pragma unroll
  for (int mi = 0; mi < 4; ++mi) {
    const int gr = m0 + mw * 64 + mi * 16 + fq * 4;
#pragma unroll
    for (int ni = 0; ni < 4; ++ni) {
      const int gc = n0 + nw * 64 + ni * 16 + fr;
#pragma unroll
      for (int r = 0; r < 4; ++r)
        atomicAdd(&out[(size_t)(gr + r) * GNN + gc], acc[mi][ni][r]);
    }
  }
}

// ================= fallback: round-4 dot2 path (proven) =================
#define TI 8
#define BT 256
#define JT 32
#define ISPL 2
#define IRANGE (1024 / ISPL)
#define CH_STRIDE (8192 * TI)

__global__ __launch_bounds__(256)
void kan_prep_dot2(const float* __restrict__ x, const float* __restrict__ knots,
                   uint32_t* __restrict__ W2, uint8_t* __restrict__ LO2) {
  const int tid = blockIdx.x * 256 + threadIdx.x;
  const int b = tid >> 10;
  const int i = tid & 1023;
  float w0, w1; int lo;
  kan_weights(x[(size_t)b * 1024 + i], knots, w0, w1, lo);
  const int idx = (i >> 3) * CH_STRIDE + b * TI + (i & 7);
  W2[idx] = h2_as_u32(cvt_pk_h2(w0, w1));
  LO2[idx] = (uint8_t)lo;
}

template <bool USE_PREP>
__global__ __launch_bounds__(256)
void kan_dot2(const float* __restrict__ x, const float* __restrict__ coef,
              const float* __restrict__ knots,
              const uint32_t* __restrict__ W2, const uint8_t* __restrict__ LO2,
              float* __restrict__ out) {
  __shared__ uint32_t Plds[TI * 12 * JT];
  const int t    = threadIdx.x;
  const int b    = blockIdx.x * BT + t;
  const int j0   = blockIdx.y * JT;
  const int cbeg = blockIdx.z * (IRANGE / TI);

  float acc[JT];
#pragma unroll
  for (int q = 0; q < JT; ++q) acc[q] = 0.0f;

  const int s_jj   = t & 31;
  const int s_iloc = t >> 5;

  for (int c = cbeg; c < cbeg + IRANGE / TI; ++c) {
    const int i0 = c * TI;
    __syncthreads();
    {
      const float* cp0 = coef + ((size_t)(j0 + s_jj) * 1024 + (i0 + s_iloc)) * 13;
      float cv[13];
#pragma unroll
      for (int s = 0; s < 13; ++s) cv[s] = cp0[s];
#pragma unroll
      for (int r = 0; r < 12; ++r) {
        half2_v h; h[0] = (_Float16)cv[r]; h[1] = (_Float16)cv[r + 1];
        const int slot = ((s_jj >> 2) + r) & 7;
        Plds[(s_iloc * 12 + r) * 32 + slot * 4 + (s_jj & 3)] = h2_as_u32(h);
      }
    }
    uint32_t wr[TI]; int lor[TI];
    if constexpr (USE_PREP) {
      const uint4* wp = (const uint4*)(W2 + (size_t)c * CH_STRIDE + b * TI);
      const uint4 wa = wp[0], wb = wp[1];
      wr[0] = wa.x; wr[1] = wa.y; wr[2] = wa.z; wr[3] = wa.w;
      wr[4] = wb.x; wr[5] = wb.y; wr[6] = wb.z; wr[7] = wb.w;
      const uint2 lb = *(const uint2*)(LO2 + (size_t)c * CH_STRIDE + b * TI);
#pragma unroll
      for (int q = 0; q < 4; ++q) { lor[q] = (lb.x >> (8 * q)) & 0xff; lor[4 + q] = (lb.y >> (8 * q)) & 0xff; }
    } else {
      const float* xrow = x + (size_t)b * 1024 + i0;
      const float4 xa = *(const float4*)(xrow);
      const float4 xb = *(const float4*)(xrow + 4);
      const float xv[TI] = {xa.x, xa.y, xa.z, xa.w, xb.x, xb.y, xb.z, xb.w};
#pragma unroll
      for (int q = 0; q < TI; ++q) {
        float w0, w1; int lo;
        kan_weights(xv[q], knots, w0, w1, lo);
        wr[q] = h2_as_u32(cvt_pk_h2(w0, w1));
        lor[q] = lo;
      }
    }
    __syncthreads();

    const uint4* P4 = (const uint4*)Plds;
#pragma unroll
    for (int ii = 0; ii < TI; ++ii) {
      const half2_v hw = u32_as_h2(wr[ii]);
      const int lo = lor[ii];
      const int base = (ii * 12 + lo) * 8;
#pragma unroll
      for (int g = 0; g < 8; ++g) {
        const uint4 v = P4[base + ((g + lo) & 7)];
        acc[4 * g + 0] = dot2f(hw, u32_as_h2(v.x), acc[4 * g + 0]);
        acc[4 * g + 1] = dot2f(hw, u32_as_h2(v.y), acc[4 * g + 1]);
        acc[4 * g + 2] = dot2f(hw, u32_as_h2(v.z), acc[4 * g + 2]);
        acc[4 * g + 3] = dot2f(hw, u32_as_h2(v.w), acc[4 * g + 3]);
      }
    }
  }

  float* orow = out + (size_t)b * 256 + j0;
#pragma unroll
  for (int q = 0; q < JT; ++q) atomicAdd(orow + q, acc[q]);
}

extern "C" void kernel_launch(void* const* d_in, const int* in_sizes, int n_in,
                              void* d_out, int out_size, void* d_ws, size_t ws_size,
                              hipStream_t stream) {
  const float* x     = (const float*)d_in[0];
  const float* coef  = (const float*)d_in[1];
  const float* knots = (const float*)d_in[2];
  float* out = (float*)d_out;

  (void)hipMemsetAsync(out, 0, (size_t)out_size * sizeof(float), stream);

  const size_t nWr = (size_t)GMM * 1024;                 // u64 records
  const size_t nB2 = (size_t)GNN * GK2;                  // f16
  const size_t needG = nWr * 8 + nB2 * 2;                // ~75.5 MB
  const size_t nW = (size_t)8192 * 1024;
  const size_t needD = nW * 5;                           // 42 MB

  if (ws_size >= needG) {
    uint64_t* Wr = (uint64_t*)d_ws;
    _Float16* B2 = (_Float16*)(Wr + nWr);
    kan_prep_W<<<dim3(8192 / 64, 1024 / 64), 256, 0, stream>>>(x, knots, Wr);
    kan_prep_B2<<<(int)((size_t)GNN * 1024 / 256), 256, 0, stream>>>(coef, (uint32_t*)B2);
    dim3 grid(GMM / BM2, GNN / BN2, KSPL2);              // (64, 2, 8) = 1024 blocks
    kan_gemm2<<<grid, 256, 0, stream>>>(Wr, B2, out);
  } else if (ws_size >= needD) {
    uint32_t* W2 = (uint32_t*)d_ws;
    uint8_t*  LO2 = (uint8_t*)(W2 + nW);
    dim3 grid(8192 / BT, 256 / JT, ISPL);
    kan_prep_dot2<<<(int)(nW / 256), 256, 0, stream>>>(x, knots, W2, LO2);
    kan_dot2<true><<<grid, BT, 0, stream>>>(x, coef, knots, W2, LO2, out);
  } else {
    dim3 grid(8192 / BT, 256 / JT, ISPL);
    kan_dot2<false><<<grid, BT, 0, stream>>>(x, coef, knots, nullptr, nullptr, out);
  }
}

// Round 9
// 228.034 us; speedup vs baseline: 1.2548x; 1.0640x over previous
//
#include <hip/hip_runtime.h>
#include <cstdint>
#include <cstddef>

// KAN layer: out[b,j] = sum_{i,k} basis_k(tanh x[b,i]) * C[j,i,k]
// basis is 2-sparse (adjacent slots lo, lo+1); pad to 16 slots/i, build MFMA
// A-fragment IN REGISTERS from 8-B records (w0,w1 f16 + lo).
// R9: single-barrier double-buffered async pipeline -- stage(it+1) issued right
// after the barrier, in flight during compute(it); drain happens at the NEXT
// barrier (after a full compute phase). Fused prep kernel, branchless tanh.

typedef _Float16 half2_v __attribute__((ext_vector_type(2)));
typedef __fp16  fp16x2  __attribute__((ext_vector_type(2)));
typedef _Float16 f16x8 __attribute__((ext_vector_type(8)));
typedef float f32x4 __attribute__((ext_vector_type(4)));

__device__ __forceinline__ half2_v u32_as_h2(uint32_t u) {
  union { uint32_t u; half2_v h; } c; c.u = u; return c.h;
}
__device__ __forceinline__ uint32_t h2_as_u32(half2_v h) {
  union { uint32_t u; half2_v h; } c; c.h = h; return c.u;
}
__device__ __forceinline__ half2_v cvt_pk_h2(float a, float b) {
  union { fp16x2 f; half2_v h; } c;
  c.f = __builtin_amdgcn_cvt_pkrtz(a, b);
  return c.h;
}
__device__ __forceinline__ float dot2f(half2_v a, half2_v b, float c) {
#if __has_builtin(__builtin_amdgcn_fdot2)
  return __builtin_amdgcn_fdot2(a, b, c, false);
#else
  return c + (float)a[0] * (float)b[0] + (float)a[1] * (float)b[1];
#endif
}
__device__ __forceinline__ uint16_t f16_bits(float v) {
  union { _Float16 h; uint16_t u; } c; c.h = (_Float16)v; return c.u;
}

__device__ __forceinline__ float fast_tanhf(float v) {
  // tanh(v) = 1 - 2/(exp(2v)+1); exact limits at +-inf, ~2ulp midrange --
  // far below the f16 quantization applied downstream.
  const float e = __expf(2.0f * v);
#if __has_builtin(__builtin_amdgcn_rcpf)
  return 1.0f - 2.0f * __builtin_amdgcn_rcpf(e + 1.0f);
#else
  return 1.0f - 2.0f / (e + 1.0f);
#endif
}

// ---- shared basis-weight computation ----
__device__ __forceinline__ void kan_weights(float xin, const float* __restrict__ knots,
                                            float& w0, float& w1, int& lo) {
  float xc = fast_tanhf(xin);
  xc = fminf(fmaxf(xc, -1.0f), 1.0f);
  int m = (int)((xc + 1.0f) * 7.5f);   // interval index; basis continuity makes +-1 ULP safe
  m = min(max(m, 0), 14);
  const float k0 = knots[m], k1 = knots[m + 1];
  const float inv = 1.0f / (k1 - k0 + 1e-8f);
  const float up = (xc - k0) * inv;
  const float dn = (k1 - xc) * inv;
  // m==0: up on slot 0 | 1<=m<=11: dn on m-1, up on m | m==12: dn on 11 | m>=13: zero
  w0 = (m == 0) ? up : ((m <= 12) ? dn : 0.0f);
  w1 = (m >= 1 && m <= 11) ? up : 0.0f;
  lo = min(max(m - 1, 0), 11);
}

__device__ __forceinline__ void load_lds16(const void* g, void* l) {
  __builtin_amdgcn_global_load_lds((const __attribute__((address_space(1))) void*)g,
                                   (__attribute__((address_space(3))) void*)l, 16, 0, 0);
}

// ================= fast path =================
#define GMM 8192
#define GNN 256
#define KI  16                 // padded slots per i
#define GK2 (1024 * KI)        // 16384
#define KSPL2 8
#define IPER (1024 / KSPL2)    // 128 i per split
#define BM2 128
#define BN2 128
#define NIT (IPER / 4)         // 32 pipeline iters (4 i each)

// Fused prep: blocks [0,2048) build Wr (records, [i][b] via LDS transpose);
// blocks [2048, 3072) build padded f16 B2.
__global__ __launch_bounds__(256)
void kan_prep_all(const float* __restrict__ x, const float* __restrict__ knots,
                  const float* __restrict__ coef,
                  uint64_t* __restrict__ Wr, uint32_t* __restrict__ B2) {
  __shared__ uint64_t T[64 * 65];
  const int bid = blockIdx.x;
  const int t = threadIdx.x;
  if (bid < 2048) {
    const int lane = t & 63, ty = t >> 6;
    const int b0 = (bid & 127) * 64, i0 = (bid >> 7) * 64;
#pragma unroll 4
    for (int r = 0; r < 16; ++r) {
      const int bl = ty * 16 + r;
      const float xv = x[(size_t)(b0 + bl) * 1024 + i0 + lane];
      float w0, w1; int lo;
      kan_weights(xv, knots, w0, w1, lo);
      const uint32_t wp = (uint32_t)f16_bits(w0) | ((uint32_t)f16_bits(w1) << 16);
      T[lane * 65 + bl] = (uint64_t)wp | ((uint64_t)(uint32_t)lo << 32);
    }
    __syncthreads();
#pragma unroll 4
    for (int r = 0; r < 16; ++r) {
      const int il = ty * 16 + r;
      Wr[(size_t)(i0 + il) * 8192 + b0 + lane] = T[il * 65 + lane];
    }
  } else {
    const int tid = (bid - 2048) * 256 + t;   // flat (j,i), 262144
    const float* cp = coef + (size_t)tid * 13;
    uint32_t w[8];
#pragma unroll
    for (int q = 0; q < 6; ++q) w[q] = h2_as_u32(cvt_pk_h2(cp[2 * q], cp[2 * q + 1]));
    w[6] = 0u; w[7] = 0u;
    uint4* p = (uint4*)(B2 + (size_t)tid * 8);
    p[0] = make_uint4(w[0], w[1], w[2], w[3]);
    p[1] = make_uint4(w[4], w[5], w[6], w[7]);
  }
}

__global__ __launch_bounds__(256)
void kan_gemm3(const uint64_t* __restrict__ Wr, const _Float16* __restrict__ B2,
               float* __restrict__ out) {
  // Double-buffered: Bs 2x16 KB (XOR-swizzled, swizzle on the global side since
  // global_load_lds LDS addr = uniform base + lane*16), Ws 2x4 KB.
  __shared__ __align__(16) char Bs[2][BN2 * 128];
  __shared__ __align__(16) uint64_t Ws[2][4 * 128];

  const int t    = threadIdx.x;
  const int lane = t & 63;
  const int wv   = t >> 6;
  const int mw   = wv & 1;          // m-half of block (64)
  const int nw   = wv >> 1;         // n-half of block (64)
  const int fr   = lane & 15;
  const int fq   = lane >> 4;
  const int m0   = blockIdx.x * BM2;
  const int n0   = blockIdx.y * BN2;
  const int i00  = blockIdx.z * IPER;
  const int fb   = (fq & 1) * 2;    // this lane's u64-word base within the 16-slot row

  f32x4 acc[4][4];
#pragma unroll
  for (int a = 0; a < 4; ++a)
#pragma unroll
    for (int b = 0; b < 4; ++b) acc[a][b] = (f32x4){0.f, 0.f, 0.f, 0.f};

  // Staging: B tile 128 rows x 64 slots = 1024 16-B chunks (4/thread), W slice
  // 4 i x 128 m = 256 chunks (1/thread). Per-thread global coords are fixed;
  // only the i-offset advances per iter.
  const int sn[4] = { (0 * 256 + t) >> 3, (1 * 256 + t) >> 3,
                      (2 * 256 + t) >> 3, (3 * 256 + t) >> 3 };
  const int sc = t & 7;   // chunk col pre-XOR (q&7 is t&7 for all s)
  const int wi = t >> 6, wm = (t & 63) * 2;

  auto stage = [&](int it) {
    const int i0 = i00 + it * 4;
    char* Bd = (char*)Bs[it & 1];
    const _Float16* Bb = B2 + (size_t)i0 * KI;
#pragma unroll
    for (int s = 0; s < 4; ++s) {
      const int c = sc ^ (sn[s] & 7);
      load_lds16(Bb + (size_t)(n0 + sn[s]) * GK2 + c * 8, Bd + (s * 256 + t) * 16);
    }
    load_lds16(Wr + (size_t)(i0 + wi) * 8192 + m0 + wm, (char*)Ws[it & 1] + t * 16);
  };

  stage(0);
  for (int it = 0; it < NIT; ++it) {
    __syncthreads();               // drains stage(it)'s loads (in flight during
                                   // compute(it-1)); all waves done with buf[(it+1)&1]
    if (it + 1 < NIT) stage(it + 1);   // flies during compute(it)

    const char* Bd = (const char*)Bs[it & 1];
    const uint64_t* Wd = Ws[it & 1];
#pragma unroll
    for (int ks = 0; ks < 2; ++ks) {
      const int iloc = ks * 2 + (fq >> 1);
      f16x8 af[4];
#pragma unroll
      for (int mi = 0; mi < 4; ++mi) {
        const uint64_t rec = Wd[iloc * 128 + mw * 64 + mi * 16 + fr];
        const uint32_t wp = (uint32_t)rec;
        const uint32_t lo = (uint32_t)(rec >> 32);
        const int s64 = (int)(lo & 3) * 16;
        const uint64_t lo64 = (uint64_t)wp << s64;
        const uint64_t hi64 = ((lo & 3) == 3) ? (uint64_t)(wp >> 16) : 0ull;
        const uint32_t q0 = lo >> 2;
        const uint64_t wA = ((uint32_t)fb == q0) ? lo64
                            : (((uint32_t)fb == q0 + 1) ? hi64 : 0ull);
        const uint64_t wB = ((uint32_t)(fb + 1) == q0) ? lo64
                            : (((uint32_t)fb == q0) ? hi64 : 0ull);
        union { uint64_t u[2]; f16x8 v; } cv;
        cv.u[0] = wA; cv.u[1] = wB;
        af[mi] = cv.v;
      }
#pragma unroll
      for (int ni = 0; ni < 4; ++ni) {
        const int row = nw * 64 + ni * 16 + fr;
        const int col = ks * 4 + fq;
        const f16x8 bf = *(const f16x8*)(Bd + (row * 8 + (col ^ (row & 7))) * 16);
#pragma unroll
        for (int mi = 0; mi < 4; ++mi)
          acc[mi][ni] = __builtin_amdgcn_mfma_f32_16x16x32_f16(af[mi], bf, acc[mi][ni], 0, 0, 0);
      }
    }
  }

#pragma unroll
  for (int mi = 0; mi < 4; ++mi) {
    const int gr = m0 + mw * 64 + mi * 16 + fq * 4;
#pragma unroll
    for (int ni = 0; ni < 4; ++ni) {
      const int gc = n0 + nw * 64 + ni * 16 + fr;
#pragma unroll
      for (int r = 0; r < 4; ++r)
        atomicAdd(&out[(size_t)(gr + r) * GNN + gc], acc[mi][ni][r]);
    }
  }
}

// ================= fallback: round-4 dot2 path (proven) =================
#define TI 8
#define BT 256
#define JT 32
#define ISPL 2
#define IRANGE (1024 / ISPL)
#define CH_STRIDE (8192 * TI)

__global__ __launch_bounds__(256)
void kan_prep_dot2(const float* __restrict__ x, const float* __restrict__ knots,
                   uint32_t* __restrict__ W2, uint8_t* __restrict__ LO2) {
  const int tid = blockIdx.x * 256 + threadIdx.x;
  const int b = tid >> 10;
  const int i = tid & 1023;
  float w0, w1; int lo;
  kan_weights(x[(size_t)b * 1024 + i], knots, w0, w1, lo);
  const int idx = (i >> 3) * CH_STRIDE + b * TI + (i & 7);
  W2[idx] = h2_as_u32(cvt_pk_h2(w0, w1));
  LO2[idx] = (uint8_t)lo;
}

template <bool USE_PREP>
__global__ __launch_bounds__(256)
void kan_dot2(const float* __restrict__ x, const float* __restrict__ coef,
              const float* __restrict__ knots,
              const uint32_t* __restrict__ W2, const uint8_t* __restrict__ LO2,
              float* __restrict__ out) {
  __shared__ uint32_t Plds[TI * 12 * JT];
  const int t    = threadIdx.x;
  const int b    = blockIdx.x * BT + t;
  const int j0   = blockIdx.y * JT;
  const int cbeg = blockIdx.z * (IRANGE / TI);

  float acc[JT];
#pragma unroll
  for (int q = 0; q < JT; ++q) acc[q] = 0.0f;

  const int s_jj   = t & 31;
  const int s_iloc = t >> 5;

  for (int c = cbeg; c < cbeg + IRANGE / TI; ++c) {
    const int i0 = c * TI;
    __syncthreads();
    {
      const float* cp0 = coef + ((size_t)(j0 + s_jj) * 1024 + (i0 + s_iloc)) * 13;
      float cv[13];
#pragma unroll
      for (int s = 0; s < 13; ++s) cv[s] = cp0[s];
#pragma unroll
      for (int r = 0; r < 12; ++r) {
        half2_v h; h[0] = (_Float16)cv[r]; h[1] = (_Float16)cv[r + 1];
        const int slot = ((s_jj >> 2) + r) & 7;
        Plds[(s_iloc * 12 + r) * 32 + slot * 4 + (s_jj & 3)] = h2_as_u32(h);
      }
    }
    uint32_t wr[TI]; int lor[TI];
    if constexpr (USE_PREP) {
      const uint4* wp = (const uint4*)(W2 + (size_t)c * CH_STRIDE + b * TI);
      const uint4 wa = wp[0], wb = wp[1];
      wr[0] = wa.x; wr[1] = wa.y; wr[2] = wa.z; wr[3] = wa.w;
      wr[4] = wb.x; wr[5] = wb.y; wr[6] = wb.z; wr[7] = wb.w;
      const uint2 lb = *(const uint2*)(LO2 + (size_t)c * CH_STRIDE + b * TI);
#pragma unroll
      for (int q = 0; q < 4; ++q) { lor[q] = (lb.x >> (8 * q)) & 0xff; lor[4 + q] = (lb.y >> (8 * q)) & 0xff; }
    } else {
      const float* xrow = x + (size_t)b * 1024 + i0;
      const float4 xa = *(const float4*)(xrow);
      const float4 xb = *(const float4*)(xrow + 4);
      const float xv[TI] = {xa.x, xa.y, xa.z, xa.w, xb.x, xb.y, xb.z, xb.w};
#pragma unroll
      for (int q = 0; q < TI; ++q) {
        float w0, w1; int lo;
        kan_weights(xv[q], knots, w0, w1, lo);
        wr[q] = h2_as_u32(cvt_pk_h2(w0, w1));
        lor[q] = lo;
      }
    }
    __syncthreads();

    const uint4* P4 = (const uint4*)Plds;
#pragma unroll
    for (int ii = 0; ii < TI; ++ii) {
      const half2_v hw = u32_as_h2(wr[ii]);
      const int lo = lor[ii];
      const int base = (ii * 12 + lo) * 8;
#pragma unroll
      for (int g = 0; g < 8; ++g) {
        const uint4 v = P4[base + ((g + lo) & 7)];
        acc[4 * g + 0] = dot2f(hw, u32_as_h2(v.x), acc[4 * g + 0]);
        acc[4 * g + 1] = dot2f(hw, u32_as_h2(v.y), acc[4 * g + 1]);
        acc[4 * g + 2] = dot2f(hw, u32_as_h2(v.z), acc[4 * g + 2]);
        acc[4 * g + 3] = dot2f(hw, u32_as_h2(v.w), acc[4 * g + 3]);
      }
    }
  }

  float* orow = out + (size_t)b * 256 + j0;
#pragma unroll
  for (int q = 0; q < JT; ++q) atomicAdd(orow + q, acc[q]);
}

extern "C" void kernel_launch(void* const* d_in, const int* in_sizes, int n_in,
                              void* d_out, int out_size, void* d_ws, size_t ws_size,
                              hipStream_t stream) {
  const float* x     = (const float*)d_in[0];
  const float* coef  = (const float*)d_in[1];
  const float* knots = (const float*)d_in[2];
  float* out = (float*)d_out;

  (void)hipMemsetAsync(out, 0, (size_t)out_size * sizeof(float), stream);

  const size_t nWr = (size_t)GMM * 1024;                 // u64 records
  const size_t nB2 = (size_t)GNN * GK2;                  // f16
  const size_t needG = nWr * 8 + nB2 * 2;                // ~75.5 MB
  const size_t nW = (size_t)8192 * 1024;
  const size_t needD = nW * 5;                           // 42 MB

  if (ws_size >= needG) {
    uint64_t* Wr = (uint64_t*)d_ws;
    _Float16* B2 = (_Float16*)(Wr + nWr);
    kan_prep_all<<<2048 + 1024, 256, 0, stream>>>(x, knots, coef, Wr, (uint32_t*)B2);
    dim3 grid(GMM / BM2, GNN / BN2, KSPL2);              // (64, 2, 8) = 1024 blocks
    kan_gemm3<<<grid, 256, 0, stream>>>(Wr, B2, out);
  } else if (ws_size >= needD) {
    uint32_t* W2 = (uint32_t*)d_ws;
    uint8_t*  LO2 = (uint8_t*)(W2 + nW);
    dim3 grid(8192 / BT, 256 / JT, ISPL);
    kan_prep_dot2<<<(int)(nW / 256), 256, 0, stream>>>(x, knots, W2, LO2);
    kan_dot2<true><<<grid, BT, 0, stream>>>(x, coef, knots, W2, LO2, out);
  } else {
    dim3 grid(8192 / BT, 256 / JT, ISPL);
    kan_dot2<false><<<grid, BT, 0, stream>>>(x, coef, knots, nullptr, nullptr, out);
  }
}